// Round 14
// baseline (155.899 us; speedup 1.0000x reference)
//
#include <hip/hip_runtime.h>
#include <cstdint>
#include <cstddef>

typedef __bf16 bf16;
typedef __bf16 bf16x4 __attribute__((ext_vector_type(4)));
typedef __bf16 bf16x8 __attribute__((ext_vector_type(8)));
typedef float f32x4 __attribute__((ext_vector_type(4)));
typedef float f32x16 __attribute__((ext_vector_type(16)));

typedef const __attribute__((address_space(1))) void* gas_ptr;
typedef __attribute__((address_space(3))) void* las_ptr;

#define GLOAD_LDS16(g, l) __builtin_amdgcn_global_load_lds((gas_ptr)(g), (las_ptr)(l), 16, 0, 0)

// ---------------- f32 -> bf16 convert (vectorized, grid-stride) ----------------
__global__ void cvt_f32_bf16(const float* __restrict__ in, bf16* __restrict__ out, int n4) {
  int i = blockIdx.x * blockDim.x + threadIdx.x;
  int stride = gridDim.x * blockDim.x;
  for (; i < n4; i += stride) {
    float4 v = reinterpret_cast<const float4*>(in)[i];
    bf16x4 o;
    o[0] = (bf16)v.x; o[1] = (bf16)v.y; o[2] = (bf16)v.z; o[3] = (bf16)v.w;
    reinterpret_cast<bf16x4*>(out)[i] = o;
  }
}

// ---------------- GEMM: C[M,N] = A[M,K] * B[N,K]^T  (both K-contiguous) --------
// r14: r13's 3-buffer 72KB LDS left only 1 block/CU resident (Occupancy ~26%,
// not the predicted 50% -- LDS granularity likely rounds 72KB past 80KB).
// The attn kernel proves the better point on this hardware: 2-buffer DRAIN
// pipeline + small LDS + 3 blocks/CU beats a deeper pipeline at 1 block/CU.
// So: BM=256 x BN=128, 8 waves, TWO buffers (48KB) -> 3 blocks/CU (144KB),
// stage(next) -> compute(cur) -> vmcnt(0)+__syncthreads (attn-proven).
// Fragment-order LDS (zero conflicts) and XCD row-chunk swizzle kept.
template <int MODE>
__global__ __launch_bounds__(512, 4) void gemm_bt(
    const bf16* __restrict__ A, const bf16* __restrict__ B,
    int M, int N, int K,
    bf16* __restrict__ outb, float* __restrict__ outf,
    const float* __restrict__ bias) {
  constexpr int BK = 32;
  __shared__ bf16 lds[2][12288];   // per buffer: A 16x512 elems | B 8x512 elems
  const int tid = threadIdx.x;
  const int l = tid & 63;
  const int w = tid >> 6;          // 0..7
  const int wr = w >> 1, wc = w & 1;
  const int lr = l & 15, lg = l >> 4;

  // XCD row-chunk swizzle: 32 row-tiles, 4 per XCD; col-major within chunk.
  const int bid = blockIdx.y * 32 + blockIdx.x;
  const int xcd = bid & 7, c = bid >> 3;
  const int brow = (xcd * 4 + (c & 3)) * 256;
  const int bcol = (c >> 2) * 128;

  // staging: wave w stages A slots {w, 8+w} and B slot w (3 loads/thread/step)
  const bf16* sa0 = A + (size_t)(brow + w * 16 + lr) * K + lg * 8;
  const bf16* sa1 = sa0 + (size_t)128 * K;
  const bf16* sb0 = B + (size_t)(bcol + w * 16 + lr) * K + lg * 8;
  const int dA0 = w * 512 + l * 8;
  const int dA1 = (8 + w) * 512 + l * 8;
  const int dB0 = 8192 + w * 512 + l * 8;

  f32x4 acc[4][4] = {};

  // prologue: stage k0=0 into buffer 0
  GLOAD_LDS16(sa0, &lds[0][dA0]);
  GLOAD_LDS16(sa1, &lds[0][dA1]);
  GLOAD_LDS16(sb0, &lds[0][dB0]);
  asm volatile("s_waitcnt vmcnt(0)" ::: "memory");
  __syncthreads();

  int p = 0;
  for (int k0 = 0; k0 < K; k0 += BK) {
    // stage NEXT K-step into p^1 (async; lands under this step's compute)
    if (k0 + BK < K) {
      GLOAD_LDS16(sa0 + (k0 + BK), &lds[p ^ 1][dA0]);
      GLOAD_LDS16(sa1 + (k0 + BK), &lds[p ^ 1][dA1]);
      GLOAD_LDS16(sb0 + (k0 + BK), &lds[p ^ 1][dB0]);
    }

    bf16x8 af[4], bfr[4];
#pragma unroll
    for (int mi = 0; mi < 4; mi++)
      af[mi] = *reinterpret_cast<const bf16x8*>(&lds[p][(wr * 4 + mi) * 512 + l * 8]);
#pragma unroll
    for (int ni = 0; ni < 4; ni++)
      bfr[ni] = *reinterpret_cast<const bf16x8*>(&lds[p][8192 + (wc * 4 + ni) * 512 + l * 8]);
#pragma unroll
    for (int mi = 0; mi < 4; mi++)
#pragma unroll
      for (int ni = 0; ni < 4; ni++)
        acc[mi][ni] = __builtin_amdgcn_mfma_f32_16x16x32_bf16(af[mi], bfr[ni], acc[mi][ni], 0, 0, 0);

    // next-tile staging complete; all waves done reading buffer p
    asm volatile("s_waitcnt vmcnt(0)" ::: "memory");
    __syncthreads();
    p ^= 1;
  }

  // epilogue: C frag mapping col = lr, row = lg*4 + r  (branch-free row-major)
#pragma unroll
  for (int mi = 0; mi < 4; mi++) {
#pragma unroll
    for (int r = 0; r < 4; r++) {
      const int m = brow + wr * 64 + mi * 16 + lg * 4 + r;
#pragma unroll
      for (int ni = 0; ni < 4; ni++) {
        const int e = bcol + wc * 64 + ni * 16 + lr;
        const float v = acc[mi][ni][r];
        if (MODE == 1) {
          outf[(size_t)m * N + e] = v + bias[e];
        } else {
          outb[(size_t)m * N + e] = (bf16)v;
        }
      }
    }
  }
}

// ---------------- V transpose: qkv cols [1536..2304) -> vtb[96][64][1024] -----
__global__ __launch_bounds__(256) void vtrans(const bf16* __restrict__ qkv,
                                              bf16* __restrict__ vtb) {
  __shared__ bf16 t[64 * 72];
  const int bh = blockIdx.x;          // 0..95
  const int b = bh / 12, h = bh % 12;
  const int nt = blockIdx.y;          // 0..15
  const int tid = threadIdx.x;
#pragma unroll
  for (int it = 0; it < 2; it++) {
    const int item = tid + it * 256;  // 0..511
    const int nl = item >> 3, c = item & 7;
    bf16x8 v = *reinterpret_cast<const bf16x8*>(
        &qkv[(size_t)(b * 1024 + nt * 64 + nl) * 2304 + 1536 + h * 64 + c * 8]);
#pragma unroll
    for (int j = 0; j < 8; j++) t[(c * 8 + j) * 72 + nl] = v[j];
  }
  __syncthreads();
#pragma unroll
  for (int it = 0; it < 2; it++) {
    const int item = tid + it * 256;
    const int d = item >> 3, c2 = item & 7;
    bf16x8 v = *reinterpret_cast<const bf16x8*>(&t[d * 72 + c2 * 8]);
    *reinterpret_cast<bf16x8*>(
        &vtb[(size_t)bh * 65536 + d * 1024 + nt * 64 + c2 * 8]) = v;
  }
}

// ---------------- Flash attention: LDS-staged, fragment-order layout ----------
// (unchanged from r9 -- this structure took attn 99.5 -> ~20 us)
__global__ __launch_bounds__(256, 3) void attn_kernel(
    const bf16* __restrict__ QKV, const bf16* __restrict__ Vt,
    bf16* __restrict__ Out) {
  __shared__ bf16 Kb[2][4096];   // 8KB per buffer, fragment-order
  __shared__ bf16 Vb[2][4096];
  const int tid = threadIdx.x;
  const int l = tid & 63;
  const int w = tid >> 6;
  const int ql = l & 31;
  const int hi = l >> 5;
  const int bh = blockIdx.x;       // 0..95 (head-major -> XCD pinning)
  const int b = bh / 12, h = bh % 12;
  const int q0 = blockIdx.y * 128 + w * 32;
  const bf16* Vh = Vt + (size_t)bh * 65536;
  constexpr float L2E = 1.4426950408889634f;

  const int kdst0 = (0 * 4 + w) * 512 + l * 8;
  const int kdst1 = (1 * 4 + w) * 512 + l * 8;
  const bf16* ksrc0 = QKV + (size_t)(b * 1024 + ql) * 2304 + 768 + h * 64 + w * 16 + hi * 8;
  const bf16* ksrc1 = ksrc0 + (size_t)32 * 2304;
  const bf16* vsrc0 = Vh + (size_t)((w & 1) * 32 + ql) * 1024 + ((0 * 4 + w) >> 1) * 16 + hi * 8;
  const bf16* vsrc1 = Vh + (size_t)((w & 1) * 32 + ql) * 1024 + ((1 * 4 + w) >> 1) * 16 + hi * 8;

  const bf16* Qrow = QKV + (size_t)(b * 1024 + q0 + ql) * 2304 + h * 64;
  bf16x8 qf[4];
#pragma unroll
  for (int s = 0; s < 4; s++)
    qf[s] = *reinterpret_cast<const bf16x8*>(&Qrow[s * 16 + hi * 8]);

  f32x16 o[2] = {};
  float ls0 = 0.f, ls1 = 0.f, ls2 = 0.f, ls3 = 0.f;

  GLOAD_LDS16(ksrc0, &Kb[0][kdst0]);
  GLOAD_LDS16(ksrc1, &Kb[0][kdst1]);
  GLOAD_LDS16(vsrc0, &Vb[0][kdst0]);
  GLOAD_LDS16(vsrc1, &Vb[0][kdst1]);
  asm volatile("s_waitcnt vmcnt(0)" ::: "memory");
  __syncthreads();

  int p = 0;
  for (int it = 0; it < 16; ++it) {
    const int kt = it * 64;
    if (it < 15) {
      GLOAD_LDS16(ksrc0 + (size_t)(kt + 64) * 2304, &Kb[p ^ 1][kdst0]);
      GLOAD_LDS16(ksrc1 + (size_t)(kt + 64) * 2304, &Kb[p ^ 1][kdst1]);
      GLOAD_LDS16(vsrc0 + (kt + 64), &Vb[p ^ 1][kdst0]);
      GLOAD_LDS16(vsrc1 + (kt + 64), &Vb[p ^ 1][kdst1]);
    }

    bf16x8 kf[8];
#pragma unroll
    for (int r = 0; r < 8; r++)
      kf[r] = *reinterpret_cast<const bf16x8*>(&Kb[p][r * 512 + l * 8]);
    f32x16 st0 = {}, st1 = {};
    __builtin_amdgcn_s_setprio(1);
#pragma unroll
    for (int s = 0; s < 4; s++) {
      st0 = __builtin_amdgcn_mfma_f32_32x32x16_bf16(kf[s], qf[s], st0, 0, 0, 0);
      st1 = __builtin_amdgcn_mfma_f32_32x32x16_bf16(kf[4 + s], qf[s], st1, 0, 0, 0);
    }
    __builtin_amdgcn_s_setprio(0);

#pragma unroll
    for (int r = 0; r < 16; r++) {
      float a0 = st0[r] * L2E, a1 = st1[r] * L2E;
      float e0, e1;
      asm("v_exp_f32 %0, %1" : "=v"(e0) : "v"(a0));
      asm("v_exp_f32 %0, %1" : "=v"(e1) : "v"(a1));
      st0[r] = e0; st1[r] = e1;
    }
#pragma unroll
    for (int r = 0; r < 16; r += 2) {
      ls0 += st0[r]; ls1 += st0[r + 1];
      ls2 += st1[r]; ls3 += st1[r + 1];
    }

    bf16x8 pfv[4];
#pragma unroll
    for (int t = 0; t < 4; t++) {
      const int c8 = (t & 1) * 8;
      const f32x16& sv = (t < 2) ? st0 : st1;
      uint32_t wA0, wA1, wB0, wB1;
      asm("v_cvt_pk_bf16_f32 %0, %1, %2" : "=v"(wA0) : "v"(sv[c8 + 0]), "v"(sv[c8 + 1]));
      asm("v_cvt_pk_bf16_f32 %0, %1, %2" : "=v"(wA1) : "v"(sv[c8 + 2]), "v"(sv[c8 + 3]));
      asm("v_cvt_pk_bf16_f32 %0, %1, %2" : "=v"(wB0) : "v"(sv[c8 + 4]), "v"(sv[c8 + 5]));
      asm("v_cvt_pk_bf16_f32 %0, %1, %2" : "=v"(wB1) : "v"(sv[c8 + 6]), "v"(sv[c8 + 7]));
      asm("v_permlane32_swap_b32 %0, %1" : "+v"(wA0), "+v"(wB0));
      asm("v_permlane32_swap_b32 %0, %1" : "+v"(wA1), "+v"(wB1));
      union { uint32_t u[4]; bf16x8 v; } pf;
      pf.u[0] = wA0; pf.u[1] = wA1; pf.u[2] = wB0; pf.u[3] = wB1;
      pfv[t] = pf.v;
    }

    bf16x8 vf[8];
#pragma unroll
    for (int r = 0; r < 8; r++)
      vf[r] = *reinterpret_cast<const bf16x8*>(&Vb[p][r * 512 + l * 8]);
    __builtin_amdgcn_s_setprio(1);
#pragma unroll
    for (int t = 0; t < 4; t++) {
      o[0] = __builtin_amdgcn_mfma_f32_32x32x16_bf16(vf[t * 2 + 0], pfv[t], o[0], 0, 0, 0);
      o[1] = __builtin_amdgcn_mfma_f32_32x32x16_bf16(vf[t * 2 + 1], pfv[t], o[1], 0, 0, 0);
    }
    __builtin_amdgcn_s_setprio(0);

    asm volatile("s_waitcnt vmcnt(0)" ::: "memory");
    __syncthreads();
    p ^= 1;
  }

  float lsum = (ls0 + ls1) + (ls2 + ls3);
  lsum += __shfl_xor(lsum, 32);
  const float rl = 1.0f / lsum;
  bf16* orow = Out + (size_t)(b * 1024 + q0 + ql) * 768 + h * 64;
#pragma unroll
  for (int dh = 0; dh < 2; dh++)
#pragma unroll
    for (int rq = 0; rq < 4; rq++) {
      union { ushort us[4]; uint2 v; } pk;
#pragma unroll
      for (int i = 0; i < 4; i++) {
        const bf16 hv = (bf16)(o[dh][rq * 4 + i] * rl);
        pk.us[i] = __builtin_bit_cast(ushort, hv);
      }
      *reinterpret_cast<uint2*>(&orow[dh * 32 + rq * 8 + hi * 4]) = pk.v;
    }
}

// ---------------- launch ------------------------------------------------------
extern "C" void kernel_launch(void* const* d_in, const int* in_sizes, int n_in,
                              void* d_out, int out_size, void* d_ws, size_t ws_size,
                              hipStream_t stream) {
  const float* x = (const float*)d_in[0];
  const float* w_qkv = (const float*)d_in[1];
  const float* w_fc = (const float*)d_in[2];
  const float* b_fc = (const float*)d_in[3];
  float* out = (float*)d_out;
  char* ws = (char*)d_ws;

  bf16* xb = (bf16*)(ws);                    // 8192x768   (dead after gemm<0>)
  bf16* vtb = (bf16*)(ws);                   // 96x64x1024 (aliases xb -- safe)
  bf16* wqkb = (bf16*)(ws + 12582912);       // 2304x768
  bf16* wfcb = (bf16*)(ws + 16121856);       // 768x768
  bf16* qkvb = (bf16*)(ws + 17301504);       // 8192x2304
  bf16* aob = (bf16*)(ws + 55050240);        // 8192x768

  cvt_f32_bf16<<<2048, 256, 0, stream>>>(x, xb, 6291456 / 4);
  cvt_f32_bf16<<<1728, 256, 0, stream>>>(w_qkv, wqkb, 1769472 / 4);
  cvt_f32_bf16<<<576, 256, 0, stream>>>(w_fc, wfcb, 589824 / 4);

  gemm_bt<0><<<dim3(32, 18), 512, 0, stream>>>(xb, wqkb, 8192, 2304, 768,
                                               qkvb, nullptr, nullptr);

  vtrans<<<dim3(96, 16), 256, 0, stream>>>(qkvb, vtb);

  attn_kernel<<<dim3(96, 8), 256, 0, stream>>>(qkvb, vtb, aob);

  gemm_bt<1><<<dim3(32, 6), 512, 0, stream>>>(aob, wfcb, 8192, 768, 768,
                                              nullptr, out, b_fc);
}

// Round 15
// 150.925 us; speedup vs baseline: 1.0330x; 1.0330x over previous
//
#include <hip/hip_runtime.h>
#include <cstdint>
#include <cstddef>

typedef __bf16 bf16;
typedef __bf16 bf16x4 __attribute__((ext_vector_type(4)));
typedef __bf16 bf16x8 __attribute__((ext_vector_type(8)));
typedef float f32x4 __attribute__((ext_vector_type(4)));
typedef float f32x16 __attribute__((ext_vector_type(16)));

typedef const __attribute__((address_space(1))) void* gas_ptr;
typedef __attribute__((address_space(3))) void* las_ptr;

#define GLOAD_LDS16(g, l) __builtin_amdgcn_global_load_lds((gas_ptr)(g), (las_ptr)(l), 16, 0, 0)

// ---------------- f32 -> bf16 convert (vectorized, grid-stride) ----------------
__global__ void cvt_f32_bf16(const float* __restrict__ in, bf16* __restrict__ out, int n4) {
  int i = blockIdx.x * blockDim.x + threadIdx.x;
  int stride = gridDim.x * blockDim.x;
  for (; i < n4; i += stride) {
    float4 v = reinterpret_cast<const float4*>(in)[i];
    bf16x4 o;
    o[0] = (bf16)v.x; o[1] = (bf16)v.y; o[2] = (bf16)v.z; o[3] = (bf16)v.w;
    reinterpret_cast<bf16x4*>(out)[i] = o;
  }
}

// ---------------- QKV GEMM: 256x256 tile, BK=64, 4-phase interleave -----------
// r15: r12-r14 proved knob-turning (buffers/tile/occupancy) is exhausted; every
// variant exposes per-step latency serially (MfmaUtil ~16%). This is the
// documented 2-phase wall (m233: stage+wait+barrier = 72% of critical path).
// Escape = phase-interleaved schedule (m196->m198 +28-41%): per K-step, 4
// phases of {ds_read frags | issue staging | setprio+16 MFMA | raw barrier}.
// Fragment-order LDS keeps every access lane-linear (0 conflicts, measured).
// Buffer safety: top-of-step vmcnt(0)+barrier; staging into q during step i
// cannot race (q's prior readers finished before the preceding barrier --
// same argument as r12/r13, race-free across re-validation).
__global__ __launch_bounds__(512, 2) void gemm256(
    const bf16* __restrict__ A, const bf16* __restrict__ B,
    int M, int N, int K, bf16* __restrict__ outb) {
  __shared__ bf16 lds[2][32768];   // per buf: A 16K elems (32KB) | B 16K elems
  const int tid = threadIdx.x;
  const int l = tid & 63;
  const int w = tid >> 6;          // 0..7
  const int wr = w >> 2, wc = w & 3;   // wave tile: rows wr*128.., cols wc*64..
  const int lr = l & 15, lg = l >> 4;

  // XCD row-chunk swizzle (288 blocks, 288%8==0): XCD owns 4 row-tiles.
  const int bid = blockIdx.y * gridDim.x + blockIdx.x;
  const int xcd = bid & 7, c = bid >> 3;
  const int brow = (xcd * 4 + (c & 3)) * 256;
  const int bcol = (c >> 2) * 256;

  // 8 staging chunks/wave: A t=0..3 (chunk w*4+t), B t=0..3.
  // chunk ai: kh=ai>>4 (k-half), s=ai&15 (16-row slot). LDS elem off =
  // kh*8192 + s*512 + l*8 (A) / +16384 (B) -> gload_lds dest is uniform
  // base + lane*16B; ds_read_b128 at the same layout is lane-linear.
  const bf16* asrc[4];
  const bf16* bsrc[4];
  int adst[4], bdst[4];
#pragma unroll
  for (int t = 0; t < 4; t++) {
    const int ai = w * 4 + t, kh = ai >> 4, s = ai & 15;
    asrc[t] = A + (size_t)(brow + s * 16 + lr) * K + kh * 32 + lg * 8;
    bsrc[t] = B + (size_t)(bcol + s * 16 + lr) * K + kh * 32 + lg * 8;
    adst[t] = kh * 8192 + s * 512 + l * 8;
    bdst[t] = 16384 + kh * 8192 + s * 512 + l * 8;
  }

  f32x4 acc[8][4] = {};

  // prologue: stage step 0 into buffer 0 (8 loads/thread... 8 loads/wave-lane)
#pragma unroll
  for (int t = 0; t < 4; t++) {
    GLOAD_LDS16(asrc[t], &lds[0][adst[t]]);
    GLOAD_LDS16(bsrc[t], &lds[0][bdst[t]]);
  }

  const int NS = K >> 6;           // 12 for K=768
  int p = 0;
  for (int step = 0; step < NS; step++) {
    const int k0 = step << 6;
    const int kn = (step + 1 < NS) ? k0 + 64 : k0;   // dummy restage on tail
    asm volatile("s_waitcnt vmcnt(0)" ::: "memory");
    __builtin_amdgcn_sched_barrier(0);
    __builtin_amdgcn_s_barrier();
    __builtin_amdgcn_sched_barrier(0);
    const int q = p ^ 1;
    bf16x8 bfr[4];

    // ---- phase 0: kh=0, rows 0..3 of wave half; stage A0,A1,B0 ----
    {
      bf16x8 af[4];
#pragma unroll
      for (int j = 0; j < 4; j++)
        bfr[j] = *reinterpret_cast<const bf16x8*>(&lds[p][16384 + (wc * 4 + j) * 512 + l * 8]);
#pragma unroll
      for (int i = 0; i < 4; i++)
        af[i] = *reinterpret_cast<const bf16x8*>(&lds[p][(wr * 8 + i) * 512 + l * 8]);
      GLOAD_LDS16(asrc[0] + kn, &lds[q][adst[0]]);
      GLOAD_LDS16(asrc[1] + kn, &lds[q][adst[1]]);
      GLOAD_LDS16(bsrc[0] + kn, &lds[q][bdst[0]]);
      __builtin_amdgcn_sched_barrier(0);
      __builtin_amdgcn_s_setprio(1);
#pragma unroll
      for (int i = 0; i < 4; i++)
#pragma unroll
        for (int j = 0; j < 4; j++)
          acc[i][j] = __builtin_amdgcn_mfma_f32_16x16x32_bf16(af[i], bfr[j], acc[i][j], 0, 0, 0);
      __builtin_amdgcn_s_setprio(0);
      __builtin_amdgcn_sched_barrier(0);
      __builtin_amdgcn_s_barrier();
    }
    // ---- phase 1: kh=0, rows 4..7; stage A2,A3,B1 (reuse bfr) ----
    {
      bf16x8 af[4];
#pragma unroll
      for (int i = 0; i < 4; i++)
        af[i] = *reinterpret_cast<const bf16x8*>(&lds[p][(wr * 8 + 4 + i) * 512 + l * 8]);
      GLOAD_LDS16(asrc[2] + kn, &lds[q][adst[2]]);
      GLOAD_LDS16(asrc[3] + kn, &lds[q][adst[3]]);
      GLOAD_LDS16(bsrc[1] + kn, &lds[q][bdst[1]]);
      __builtin_amdgcn_sched_barrier(0);
      __builtin_amdgcn_s_setprio(1);
#pragma unroll
      for (int i = 0; i < 4; i++)
#pragma unroll
        for (int j = 0; j < 4; j++)
          acc[4 + i][j] = __builtin_amdgcn_mfma_f32_16x16x32_bf16(af[i], bfr[j], acc[4 + i][j], 0, 0, 0);
      __builtin_amdgcn_s_setprio(0);
      __builtin_amdgcn_sched_barrier(0);
      __builtin_amdgcn_s_barrier();
    }
    // ---- phase 2: kh=1, rows 0..3; stage B2,B3 ----
    {
      bf16x8 af[4];
#pragma unroll
      for (int j = 0; j < 4; j++)
        bfr[j] = *reinterpret_cast<const bf16x8*>(&lds[p][16384 + 8192 + (wc * 4 + j) * 512 + l * 8]);
#pragma unroll
      for (int i = 0; i < 4; i++)
        af[i] = *reinterpret_cast<const bf16x8*>(&lds[p][8192 + (wr * 8 + i) * 512 + l * 8]);
      GLOAD_LDS16(bsrc[2] + kn, &lds[q][bdst[2]]);
      GLOAD_LDS16(bsrc[3] + kn, &lds[q][bdst[3]]);
      __builtin_amdgcn_sched_barrier(0);
      __builtin_amdgcn_s_setprio(1);
#pragma unroll
      for (int i = 0; i < 4; i++)
#pragma unroll
        for (int j = 0; j < 4; j++)
          acc[i][j] = __builtin_amdgcn_mfma_f32_16x16x32_bf16(af[i], bfr[j], acc[i][j], 0, 0, 0);
      __builtin_amdgcn_s_setprio(0);
      __builtin_amdgcn_sched_barrier(0);
      __builtin_amdgcn_s_barrier();
    }
    // ---- phase 3: kh=1, rows 4..7 (reuse bfr; no staging) ----
    {
      bf16x8 af[4];
#pragma unroll
      for (int i = 0; i < 4; i++)
        af[i] = *reinterpret_cast<const bf16x8*>(&lds[p][8192 + (wr * 8 + 4 + i) * 512 + l * 8]);
      __builtin_amdgcn_sched_barrier(0);
      __builtin_amdgcn_s_setprio(1);
#pragma unroll
      for (int i = 0; i < 4; i++)
#pragma unroll
        for (int j = 0; j < 4; j++)
          acc[4 + i][j] = __builtin_amdgcn_mfma_f32_16x16x32_bf16(af[i], bfr[j], acc[4 + i][j], 0, 0, 0);
      __builtin_amdgcn_s_setprio(0);
      // no trailing barrier: next step's top vmcnt(0)+barrier covers it
    }
    p = q;
  }

  // epilogue: C frag mapping col = lr, row = lg*4 + r
#pragma unroll
  for (int si = 0; si < 8; si++)
#pragma unroll
    for (int r = 0; r < 4; r++) {
      const int m = brow + (wr * 8 + si) * 16 + lg * 4 + r;
#pragma unroll
      for (int j = 0; j < 4; j++) {
        const int e = bcol + (wc * 4 + j) * 16 + lr;
        outb[(size_t)m * N + e] = (bf16)acc[si][j][r];
      }
    }
}

// ---------------- GEMM (r13 3-buf counted): used for the FC projection --------
template <int MODE>
__global__ __launch_bounds__(512, 4) void gemm_bt(
    const bf16* __restrict__ A, const bf16* __restrict__ B,
    int M, int N, int K,
    bf16* __restrict__ outb, float* __restrict__ outf,
    const float* __restrict__ bias) {
  constexpr int BK = 32;
  __shared__ bf16 lds[3][12288];   // per buffer: A 16x512 elems | B 8x512 elems
  const int tid = threadIdx.x;
  const int l = tid & 63;
  const int w = tid >> 6;          // 0..7
  const int wr = w >> 1, wc = w & 1;
  const int lr = l & 15, lg = l >> 4;

  const int bid = blockIdx.y * 32 + blockIdx.x;
  const int xcd = bid & 7, c = bid >> 3;
  const int brow = (xcd * 4 + (c & 3)) * 256;
  const int bcol = (c >> 2) * 128;

  const bf16* sa0 = A + (size_t)(brow + w * 16 + lr) * K + lg * 8;
  const bf16* sa1 = sa0 + (size_t)128 * K;
  const bf16* sb0 = B + (size_t)(bcol + w * 16 + lr) * K + lg * 8;
  const int dA0 = w * 512 + l * 8;
  const int dA1 = (8 + w) * 512 + l * 8;
  const int dB0 = 8192 + w * 512 + l * 8;

  f32x4 acc[4][4] = {};

  GLOAD_LDS16(sa0, &lds[0][dA0]);
  GLOAD_LDS16(sa1, &lds[0][dA1]);
  GLOAD_LDS16(sb0, &lds[0][dB0]);
  GLOAD_LDS16(sa0 + BK, &lds[1][dA0]);
  GLOAD_LDS16(sa1 + BK, &lds[1][dA1]);
  GLOAD_LDS16(sb0 + BK, &lds[1][dB0]);

  int p = 0;
  for (int k0 = 0; k0 < K; k0 += BK) {
    asm volatile("s_waitcnt vmcnt(3)" ::: "memory");
    __builtin_amdgcn_sched_barrier(0);
    __builtin_amdgcn_s_barrier();
    __builtin_amdgcn_sched_barrier(0);

    int kn = k0 + 2 * BK;
    if (kn >= K) kn = k0;
    const int pt = (p >= 1) ? p - 1 : 2;   // (p+2)%3
    GLOAD_LDS16(sa0 + kn, &lds[pt][dA0]);
    GLOAD_LDS16(sa1 + kn, &lds[pt][dA1]);
    GLOAD_LDS16(sb0 + kn, &lds[pt][dB0]);

    bf16x8 af[4], bfr[4];
#pragma unroll
    for (int mi = 0; mi < 4; mi++)
      af[mi] = *reinterpret_cast<const bf16x8*>(&lds[p][(wr * 4 + mi) * 512 + l * 8]);
#pragma unroll
    for (int ni = 0; ni < 4; ni++)
      bfr[ni] = *reinterpret_cast<const bf16x8*>(&lds[p][8192 + (wc * 4 + ni) * 512 + l * 8]);
#pragma unroll
    for (int mi = 0; mi < 4; mi++)
#pragma unroll
      for (int ni = 0; ni < 4; ni++)
        acc[mi][ni] = __builtin_amdgcn_mfma_f32_16x16x32_bf16(af[mi], bfr[ni], acc[mi][ni], 0, 0, 0);
    p = (p == 2) ? 0 : p + 1;
  }

#pragma unroll
  for (int mi = 0; mi < 4; mi++) {
#pragma unroll
    for (int r = 0; r < 4; r++) {
      const int m = brow + wr * 64 + mi * 16 + lg * 4 + r;
#pragma unroll
      for (int ni = 0; ni < 4; ni++) {
        const int e = bcol + wc * 64 + ni * 16 + lr;
        const float v = acc[mi][ni][r];
        if (MODE == 1) {
          outf[(size_t)m * N + e] = v + bias[e];
        } else {
          outb[(size_t)m * N + e] = (bf16)v;
        }
      }
    }
  }
}

// ---------------- V transpose: qkv cols [1536..2304) -> vtb[96][64][1024] -----
__global__ __launch_bounds__(256) void vtrans(const bf16* __restrict__ qkv,
                                              bf16* __restrict__ vtb) {
  __shared__ bf16 t[64 * 72];
  const int bh = blockIdx.x;          // 0..95
  const int b = bh / 12, h = bh % 12;
  const int nt = blockIdx.y;          // 0..15
  const int tid = threadIdx.x;
#pragma unroll
  for (int it = 0; it < 2; it++) {
    const int item = tid + it * 256;  // 0..511
    const int nl = item >> 3, c = item & 7;
    bf16x8 v = *reinterpret_cast<const bf16x8*>(
        &qkv[(size_t)(b * 1024 + nt * 64 + nl) * 2304 + 1536 + h * 64 + c * 8]);
#pragma unroll
    for (int j = 0; j < 8; j++) t[(c * 8 + j) * 72 + nl] = v[j];
  }
  __syncthreads();
#pragma unroll
  for (int it = 0; it < 2; it++) {
    const int item = tid + it * 256;
    const int d = item >> 3, c2 = item & 7;
    bf16x8 v = *reinterpret_cast<const bf16x8*>(&t[d * 72 + c2 * 8]);
    *reinterpret_cast<bf16x8*>(
        &vtb[(size_t)bh * 65536 + d * 1024 + nt * 64 + c2 * 8]) = v;
  }
}

// ---------------- Flash attention: LDS-staged, fragment-order layout ----------
// (unchanged from r9 -- this structure took attn 99.5 -> ~20 us)
__global__ __launch_bounds__(256, 3) void attn_kernel(
    const bf16* __restrict__ QKV, const bf16* __restrict__ Vt,
    bf16* __restrict__ Out) {
  __shared__ bf16 Kb[2][4096];   // 8KB per buffer, fragment-order
  __shared__ bf16 Vb[2][4096];
  const int tid = threadIdx.x;
  const int l = tid & 63;
  const int w = tid >> 6;
  const int ql = l & 31;
  const int hi = l >> 5;
  const int bh = blockIdx.x;       // 0..95 (head-major -> XCD pinning)
  const int b = bh / 12, h = bh % 12;
  const int q0 = blockIdx.y * 128 + w * 32;
  const bf16* Vh = Vt + (size_t)bh * 65536;
  constexpr float L2E = 1.4426950408889634f;

  const int kdst0 = (0 * 4 + w) * 512 + l * 8;
  const int kdst1 = (1 * 4 + w) * 512 + l * 8;
  const bf16* ksrc0 = QKV + (size_t)(b * 1024 + ql) * 2304 + 768 + h * 64 + w * 16 + hi * 8;
  const bf16* ksrc1 = ksrc0 + (size_t)32 * 2304;
  const bf16* vsrc0 = Vh + (size_t)((w & 1) * 32 + ql) * 1024 + ((0 * 4 + w) >> 1) * 16 + hi * 8;
  const bf16* vsrc1 = Vh + (size_t)((w & 1) * 32 + ql) * 1024 + ((1 * 4 + w) >> 1) * 16 + hi * 8;

  const bf16* Qrow = QKV + (size_t)(b * 1024 + q0 + ql) * 2304 + h * 64;
  bf16x8 qf[4];
#pragma unroll
  for (int s = 0; s < 4; s++)
    qf[s] = *reinterpret_cast<const bf16x8*>(&Qrow[s * 16 + hi * 8]);

  f32x16 o[2] = {};
  float ls0 = 0.f, ls1 = 0.f, ls2 = 0.f, ls3 = 0.f;

  GLOAD_LDS16(ksrc0, &Kb[0][kdst0]);
  GLOAD_LDS16(ksrc1, &Kb[0][kdst1]);
  GLOAD_LDS16(vsrc0, &Vb[0][kdst0]);
  GLOAD_LDS16(vsrc1, &Vb[0][kdst1]);
  asm volatile("s_waitcnt vmcnt(0)" ::: "memory");
  __syncthreads();

  int p = 0;
  for (int it = 0; it < 16; ++it) {
    const int kt = it * 64;
    if (it < 15) {
      GLOAD_LDS16(ksrc0 + (size_t)(kt + 64) * 2304, &Kb[p ^ 1][kdst0]);
      GLOAD_LDS16(ksrc1 + (size_t)(kt + 64) * 2304, &Kb[p ^ 1][kdst1]);
      GLOAD_LDS16(vsrc0 + (kt + 64), &Vb[p ^ 1][kdst0]);
      GLOAD_LDS16(vsrc1 + (kt + 64), &Vb[p ^ 1][kdst1]);
    }

    bf16x8 kf[8];
#pragma unroll
    for (int r = 0; r < 8; r++)
      kf[r] = *reinterpret_cast<const bf16x8*>(&Kb[p][r * 512 + l * 8]);
    f32x16 st0 = {}, st1 = {};
    __builtin_amdgcn_s_setprio(1);
#pragma unroll
    for (int s = 0; s < 4; s++) {
      st0 = __builtin_amdgcn_mfma_f32_32x32x16_bf16(kf[s], qf[s], st0, 0, 0, 0);
      st1 = __builtin_amdgcn_mfma_f32_32x32x16_bf16(kf[4 + s], qf[s], st1, 0, 0, 0);
    }
    __builtin_amdgcn_s_setprio(0);

#pragma unroll
    for (int r = 0; r < 16; r++) {
      float a0 = st0[r] * L2E, a1 = st1[r] * L2E;
      float e0, e1;
      asm("v_exp_f32 %0, %1" : "=v"(e0) : "v"(a0));
      asm("v_exp_f32 %0, %1" : "=v"(e1) : "v"(a1));
      st0[r] = e0; st1[r] = e1;
    }
#pragma unroll
    for (int r = 0; r < 16; r += 2) {
      ls0 += st0[r]; ls1 += st0[r + 1];
      ls2 += st1[r]; ls3 += st1[r + 1];
    }

    bf16x8 pfv[4];
#pragma unroll
    for (int t = 0; t < 4; t++) {
      const int c8 = (t & 1) * 8;
      const f32x16& sv = (t < 2) ? st0 : st1;
      uint32_t wA0, wA1, wB0, wB1;
      asm("v_cvt_pk_bf16_f32 %0, %1, %2" : "=v"(wA0) : "v"(sv[c8 + 0]), "v"(sv[c8 + 1]));
      asm("v_cvt_pk_bf16_f32 %0, %1, %2" : "=v"(wA1) : "v"(sv[c8 + 2]), "v"(sv[c8 + 3]));
      asm("v_cvt_pk_bf16_f32 %0, %1, %2" : "=v"(wB0) : "v"(sv[c8 + 4]), "v"(sv[c8 + 5]));
      asm("v_cvt_pk_bf16_f32 %0, %1, %2" : "=v"(wB1) : "v"(sv[c8 + 6]), "v"(sv[c8 + 7]));
      asm("v_permlane32_swap_b32 %0, %1" : "+v"(wA0), "+v"(wB0));
      asm("v_permlane32_swap_b32 %0, %1" : "+v"(wA1), "+v"(wB1));
      union { uint32_t u[4]; bf16x8 v; } pf;
      pf.u[0] = wA0; pf.u[1] = wA1; pf.u[2] = wB0; pf.u[3] = wB1;
      pfv[t] = pf.v;
    }

    bf16x8 vf[8];
#pragma unroll
    for (int r = 0; r < 8; r++)
      vf[r] = *reinterpret_cast<const bf16x8*>(&Vb[p][r * 512 + l * 8]);
    __builtin_amdgcn_s_setprio(1);
#pragma unroll
    for (int t = 0; t < 4; t++) {
      o[0] = __builtin_amdgcn_mfma_f32_32x32x16_bf16(vf[t * 2 + 0], pfv[t], o[0], 0, 0, 0);
      o[1] = __builtin_amdgcn_mfma_f32_32x32x16_bf16(vf[t * 2 + 1], pfv[t], o[1], 0, 0, 0);
    }
    __builtin_amdgcn_s_setprio(0);

    asm volatile("s_waitcnt vmcnt(0)" ::: "memory");
    __syncthreads();
    p ^= 1;
  }

  float lsum = (ls0 + ls1) + (ls2 + ls3);
  lsum += __shfl_xor(lsum, 32);
  const float rl = 1.0f / lsum;
  bf16* orow = Out + (size_t)(b * 1024 + q0 + ql) * 768 + h * 64;
#pragma unroll
  for (int dh = 0; dh < 2; dh++)
#pragma unroll
    for (int rq = 0; rq < 4; rq++) {
      union { ushort us[4]; uint2 v; } pk;
#pragma unroll
      for (int i = 0; i < 4; i++) {
        const bf16 hv = (bf16)(o[dh][rq * 4 + i] * rl);
        pk.us[i] = __builtin_bit_cast(ushort, hv);
      }
      *reinterpret_cast<uint2*>(&orow[dh * 32 + rq * 8 + hi * 4]) = pk.v;
    }
}

// ---------------- launch ------------------------------------------------------
extern "C" void kernel_launch(void* const* d_in, const int* in_sizes, int n_in,
                              void* d_out, int out_size, void* d_ws, size_t ws_size,
                              hipStream_t stream) {
  const float* x = (const float*)d_in[0];
  const float* w_qkv = (const float*)d_in[1];
  const float* w_fc = (const float*)d_in[2];
  const float* b_fc = (const float*)d_in[3];
  float* out = (float*)d_out;
  char* ws = (char*)d_ws;

  bf16* xb = (bf16*)(ws);                    // 8192x768   (dead after gemm256)
  bf16* vtb = (bf16*)(ws);                   // 96x64x1024 (aliases xb -- safe)
  bf16* wqkb = (bf16*)(ws + 12582912);       // 2304x768
  bf16* wfcb = (bf16*)(ws + 16121856);       // 768x768
  bf16* qkvb = (bf16*)(ws + 17301504);       // 8192x2304
  bf16* aob = (bf16*)(ws + 55050240);        // 8192x768

  cvt_f32_bf16<<<2048, 256, 0, stream>>>(x, xb, 6291456 / 4);
  cvt_f32_bf16<<<1728, 256, 0, stream>>>(w_qkv, wqkb, 1769472 / 4);
  cvt_f32_bf16<<<576, 256, 0, stream>>>(w_fc, wfcb, 589824 / 4);

  gemm256<<<dim3(32, 9), 512, 0, stream>>>(xb, wqkb, 8192, 2304, 768, qkvb);

  vtrans<<<dim3(96, 16), 256, 0, stream>>>(qkvb, vtb);

  attn_kernel<<<dim3(96, 8), 256, 0, stream>>>(qkvb, vtb, aob);

  gemm_bt<1><<<dim3(32, 6), 512, 0, stream>>>(aob, wfcb, 8192, 768, 768,
                                              nullptr, out, b_fc);
}

// Round 16
// 144.100 us; speedup vs baseline: 1.0819x; 1.0474x over previous
//
#include <hip/hip_runtime.h>
#include <cstdint>
#include <cstddef>

typedef __bf16 bf16;
typedef __bf16 bf16x4 __attribute__((ext_vector_type(4)));
typedef __bf16 bf16x8 __attribute__((ext_vector_type(8)));
typedef float f32x4 __attribute__((ext_vector_type(4)));
typedef float f32x16 __attribute__((ext_vector_type(16)));

typedef const __attribute__((address_space(1))) void* gas_ptr;
typedef __attribute__((address_space(3))) void* las_ptr;

#define GLOAD_LDS16(g, l) __builtin_amdgcn_global_load_lds((gas_ptr)(g), (las_ptr)(l), 16, 0, 0)

// ---------------- f32 -> bf16 convert (vectorized, grid-stride) ----------------
__global__ void cvt_f32_bf16(const float* __restrict__ in, bf16* __restrict__ out, int n4) {
  int i = blockIdx.x * blockDim.x + threadIdx.x;
  int stride = gridDim.x * blockDim.x;
  for (; i < n4; i += stride) {
    float4 v = reinterpret_cast<const float4*>(in)[i];
    bf16x4 o;
    o[0] = (bf16)v.x; o[1] = (bf16)v.y; o[2] = (bf16)v.z; o[3] = (bf16)v.w;
    reinterpret_cast<bf16x4*>(out)[i] = o;
  }
}

// ---------------- QKV GEMM: 256x256, BK=64, COUNTED vmcnt(4) pipeline ---------
// r16: r15's per-CU rate was 742-TF-class but (a) the per-step vmcnt(0) drain
// made it the m218-V1 "8-phase-with-drain0" case, and (b) the 288-block grid
// wastes round 2. This round changes ONE thing: counted waits (T4).
//   Per wave per K-step, 8 staged chunks: {A-kh0 x2, B-kh0 x2, A-kh1 x2,
//   B-kh1 x2}. Two sub-steps; at each sync: s_waitcnt vmcnt(4) -> exactly the
//   needed half-step is complete, 4 loads ALWAYS stay in flight (never drain).
//   Sub-step A: wait kh0(i) | read kh0 frags | issue kh0(i+1) | 32 MFMA.
//   Sub-step B: wait kh1(i) | read kh1 frags | issue kh1(i+1) | 32 MFMA.
// Race-free: a buffer's readers finish (lgkm waits precede their MFMAs, which
// precede the barrier) before the barrier after which it is rewritten.
// Fragment-order LDS (lane-linear, 0 conflicts) and XCD swizzle unchanged.
__global__ __launch_bounds__(512, 2) void gemm256(
    const bf16* __restrict__ A, const bf16* __restrict__ B,
    int M, int N, int K, bf16* __restrict__ outb) {
  __shared__ bf16 lds[2][32768];   // per buf: A 16K elems | B 16K elems
  const int tid = threadIdx.x;
  const int l = tid & 63;
  const int w = tid >> 6;          // 0..7
  const int wr = w >> 2, wc = w & 3;   // wave tile: rows wr*128.., cols wc*64..
  const int lr = l & 15, lg = l >> 4;

  // XCD row-chunk swizzle (288 blocks, 288%8==0): XCD owns 4 row-tiles.
  const int bid = blockIdx.y * gridDim.x + blockIdx.x;
  const int xcd = bid & 7, c = bid >> 3;
  const int brow = (xcd * 4 + (c & 3)) * 256;
  const int bcol = (c >> 2) * 256;

  // staging: wave w owns 16-row slots {2w, 2w+1} of both A and B; per k-half
  // it stages 2 A-chunks + 2 B-chunks (1KB each). LDS elem = kh*8192 +
  // slot*512 + l*8 (A) / +16384 (B): gload_lds dest = uniform base + lane*16B.
  const int s0 = w * 2, s1 = w * 2 + 1;
  const bf16* aS0 = A + (size_t)(brow + s0 * 16 + lr) * K + lg * 8;
  const bf16* aS1 = A + (size_t)(brow + s1 * 16 + lr) * K + lg * 8;
  const bf16* bS0 = B + (size_t)(bcol + s0 * 16 + lr) * K + lg * 8;
  const bf16* bS1 = B + (size_t)(bcol + s1 * 16 + lr) * K + lg * 8;
  const int dA0 = s0 * 512 + l * 8, dA1 = s1 * 512 + l * 8;
  const int dB0 = 16384 + dA0, dB1 = 16384 + dA1;

  f32x4 acc[8][4] = {};

  // prologue: stage step 0 (kh0 first, then kh1 -- oldest-first order matters)
  GLOAD_LDS16(aS0, &lds[0][dA0]);
  GLOAD_LDS16(aS1, &lds[0][dA1]);
  GLOAD_LDS16(bS0, &lds[0][dB0]);
  GLOAD_LDS16(bS1, &lds[0][dB1]);
  GLOAD_LDS16(aS0 + 32, &lds[0][dA0 + 8192]);
  GLOAD_LDS16(aS1 + 32, &lds[0][dA1 + 8192]);
  GLOAD_LDS16(bS0 + 32, &lds[0][dB0 + 8192]);
  GLOAD_LDS16(bS1 + 32, &lds[0][dB1 + 8192]);

  const int NS = K >> 6;           // 12 for K=768
  int p = 0;
  for (int step = 0; step < NS; step++) {
    const int k0 = step << 6;
    const int kn = (step + 1 < NS) ? k0 + 64 : k0;   // dummy restage on tail
    const int q = p ^ 1;
    bf16x8 bfr[4], af[4];

    // ===== sub-step A: k-half 0 =====
    asm volatile("s_waitcnt vmcnt(4)" ::: "memory");   // kh0(i) done; kh1(i) flying
    __builtin_amdgcn_sched_barrier(0);
    __builtin_amdgcn_s_barrier();
    __builtin_amdgcn_sched_barrier(0);
#pragma unroll
    for (int j = 0; j < 4; j++)
      bfr[j] = *reinterpret_cast<const bf16x8*>(&lds[p][16384 + (wc * 4 + j) * 512 + l * 8]);
#pragma unroll
    for (int i = 0; i < 4; i++)
      af[i] = *reinterpret_cast<const bf16x8*>(&lds[p][(wr * 8 + i) * 512 + l * 8]);
    GLOAD_LDS16(aS0 + kn, &lds[q][dA0]);               // issue kh0(i+1)
    GLOAD_LDS16(aS1 + kn, &lds[q][dA1]);
    GLOAD_LDS16(bS0 + kn, &lds[q][dB0]);
    GLOAD_LDS16(bS1 + kn, &lds[q][dB1]);
    __builtin_amdgcn_sched_barrier(0);
    __builtin_amdgcn_s_setprio(1);
#pragma unroll
    for (int i = 0; i < 4; i++)
#pragma unroll
      for (int j = 0; j < 4; j++)
        acc[i][j] = __builtin_amdgcn_mfma_f32_16x16x32_bf16(af[i], bfr[j], acc[i][j], 0, 0, 0);
    __builtin_amdgcn_s_setprio(0);
#pragma unroll
    for (int i = 0; i < 4; i++)
      af[i] = *reinterpret_cast<const bf16x8*>(&lds[p][(wr * 8 + 4 + i) * 512 + l * 8]);
    __builtin_amdgcn_s_setprio(1);
#pragma unroll
    for (int i = 0; i < 4; i++)
#pragma unroll
      for (int j = 0; j < 4; j++)
        acc[4 + i][j] = __builtin_amdgcn_mfma_f32_16x16x32_bf16(af[i], bfr[j], acc[4 + i][j], 0, 0, 0);
    __builtin_amdgcn_s_setprio(0);

    // ===== sub-step B: k-half 1 =====
    asm volatile("s_waitcnt vmcnt(4)" ::: "memory");   // kh1(i) done; kh0(i+1) flying
    __builtin_amdgcn_sched_barrier(0);
    __builtin_amdgcn_s_barrier();
    __builtin_amdgcn_sched_barrier(0);
#pragma unroll
    for (int j = 0; j < 4; j++)
      bfr[j] = *reinterpret_cast<const bf16x8*>(&lds[p][16384 + 8192 + (wc * 4 + j) * 512 + l * 8]);
#pragma unroll
    for (int i = 0; i < 4; i++)
      af[i] = *reinterpret_cast<const bf16x8*>(&lds[p][8192 + (wr * 8 + i) * 512 + l * 8]);
    GLOAD_LDS16(aS0 + kn + 32, &lds[q][dA0 + 8192]);   // issue kh1(i+1)
    GLOAD_LDS16(aS1 + kn + 32, &lds[q][dA1 + 8192]);
    GLOAD_LDS16(bS0 + kn + 32, &lds[q][dB0 + 8192]);
    GLOAD_LDS16(bS1 + kn + 32, &lds[q][dB1 + 8192]);
    __builtin_amdgcn_sched_barrier(0);
    __builtin_amdgcn_s_setprio(1);
#pragma unroll
    for (int i = 0; i < 4; i++)
#pragma unroll
      for (int j = 0; j < 4; j++)
        acc[i][j] = __builtin_amdgcn_mfma_f32_16x16x32_bf16(af[i], bfr[j], acc[i][j], 0, 0, 0);
    __builtin_amdgcn_s_setprio(0);
#pragma unroll
    for (int i = 0; i < 4; i++)
      af[i] = *reinterpret_cast<const bf16x8*>(&lds[p][8192 + (wr * 8 + 4 + i) * 512 + l * 8]);
    __builtin_amdgcn_s_setprio(1);
#pragma unroll
    for (int i = 0; i < 4; i++)
#pragma unroll
      for (int j = 0; j < 4; j++)
        acc[4 + i][j] = __builtin_amdgcn_mfma_f32_16x16x32_bf16(af[i], bfr[j], acc[4 + i][j], 0, 0, 0);
    __builtin_amdgcn_s_setprio(0);

    p = q;
  }
  asm volatile("s_waitcnt vmcnt(0)" ::: "memory");     // drain dummies pre-exit

  // epilogue: C frag mapping col = lr, row = lg*4 + r
#pragma unroll
  for (int si = 0; si < 8; si++)
#pragma unroll
    for (int r = 0; r < 4; r++) {
      const int m = brow + (wr * 8 + si) * 16 + lg * 4 + r;
#pragma unroll
      for (int j = 0; j < 4; j++) {
        const int e = bcol + (wc * 4 + j) * 16 + lr;
        outb[(size_t)m * N + e] = (bf16)acc[si][j][r];
      }
    }
}

// ---------------- GEMM (r13 3-buf counted): used for the FC projection --------
template <int MODE>
__global__ __launch_bounds__(512, 4) void gemm_bt(
    const bf16* __restrict__ A, const bf16* __restrict__ B,
    int M, int N, int K,
    bf16* __restrict__ outb, float* __restrict__ outf,
    const float* __restrict__ bias) {
  constexpr int BK = 32;
  __shared__ bf16 lds[3][12288];   // per buffer: A 16x512 elems | B 8x512 elems
  const int tid = threadIdx.x;
  const int l = tid & 63;
  const int w = tid >> 6;          // 0..7
  const int wr = w >> 1, wc = w & 1;
  const int lr = l & 15, lg = l >> 4;

  const int bid = blockIdx.y * 32 + blockIdx.x;
  const int xcd = bid & 7, c = bid >> 3;
  const int brow = (xcd * 4 + (c & 3)) * 256;
  const int bcol = (c >> 2) * 128;

  const bf16* sa0 = A + (size_t)(brow + w * 16 + lr) * K + lg * 8;
  const bf16* sa1 = sa0 + (size_t)128 * K;
  const bf16* sb0 = B + (size_t)(bcol + w * 16 + lr) * K + lg * 8;
  const int dA0 = w * 512 + l * 8;
  const int dA1 = (8 + w) * 512 + l * 8;
  const int dB0 = 8192 + w * 512 + l * 8;

  f32x4 acc[4][4] = {};

  GLOAD_LDS16(sa0, &lds[0][dA0]);
  GLOAD_LDS16(sa1, &lds[0][dA1]);
  GLOAD_LDS16(sb0, &lds[0][dB0]);
  GLOAD_LDS16(sa0 + BK, &lds[1][dA0]);
  GLOAD_LDS16(sa1 + BK, &lds[1][dA1]);
  GLOAD_LDS16(sb0 + BK, &lds[1][dB0]);

  int p = 0;
  for (int k0 = 0; k0 < K; k0 += BK) {
    asm volatile("s_waitcnt vmcnt(3)" ::: "memory");
    __builtin_amdgcn_sched_barrier(0);
    __builtin_amdgcn_s_barrier();
    __builtin_amdgcn_sched_barrier(0);

    int kn = k0 + 2 * BK;
    if (kn >= K) kn = k0;
    const int pt = (p >= 1) ? p - 1 : 2;   // (p+2)%3
    GLOAD_LDS16(sa0 + kn, &lds[pt][dA0]);
    GLOAD_LDS16(sa1 + kn, &lds[pt][dA1]);
    GLOAD_LDS16(sb0 + kn, &lds[pt][dB0]);

    bf16x8 af[4], bfr[4];
#pragma unroll
    for (int mi = 0; mi < 4; mi++)
      af[mi] = *reinterpret_cast<const bf16x8*>(&lds[p][(wr * 4 + mi) * 512 + l * 8]);
#pragma unroll
    for (int ni = 0; ni < 4; ni++)
      bfr[ni] = *reinterpret_cast<const bf16x8*>(&lds[p][8192 + (wc * 4 + ni) * 512 + l * 8]);
#pragma unroll
    for (int mi = 0; mi < 4; mi++)
#pragma unroll
      for (int ni = 0; ni < 4; ni++)
        acc[mi][ni] = __builtin_amdgcn_mfma_f32_16x16x32_bf16(af[mi], bfr[ni], acc[mi][ni], 0, 0, 0);
    p = (p == 2) ? 0 : p + 1;
  }

#pragma unroll
  for (int mi = 0; mi < 4; mi++) {
#pragma unroll
    for (int r = 0; r < 4; r++) {
      const int m = brow + wr * 64 + mi * 16 + lg * 4 + r;
#pragma unroll
      for (int ni = 0; ni < 4; ni++) {
        const int e = bcol + wc * 64 + ni * 16 + lr;
        const float v = acc[mi][ni][r];
        if (MODE == 1) {
          outf[(size_t)m * N + e] = v + bias[e];
        } else {
          outb[(size_t)m * N + e] = (bf16)v;
        }
      }
    }
  }
}

// ---------------- V transpose: qkv cols [1536..2304) -> vtb[96][64][1024] -----
__global__ __launch_bounds__(256) void vtrans(const bf16* __restrict__ qkv,
                                              bf16* __restrict__ vtb) {
  __shared__ bf16 t[64 * 72];
  const int bh = blockIdx.x;          // 0..95
  const int b = bh / 12, h = bh % 12;
  const int nt = blockIdx.y;          // 0..15
  const int tid = threadIdx.x;
#pragma unroll
  for (int it = 0; it < 2; it++) {
    const int item = tid + it * 256;  // 0..511
    const int nl = item >> 3, c = item & 7;
    bf16x8 v = *reinterpret_cast<const bf16x8*>(
        &qkv[(size_t)(b * 1024 + nt * 64 + nl) * 2304 + 1536 + h * 64 + c * 8]);
#pragma unroll
    for (int j = 0; j < 8; j++) t[(c * 8 + j) * 72 + nl] = v[j];
  }
  __syncthreads();
#pragma unroll
  for (int it = 0; it < 2; it++) {
    const int item = tid + it * 256;
    const int d = item >> 3, c2 = item & 7;
    bf16x8 v = *reinterpret_cast<const bf16x8*>(&t[d * 72 + c2 * 8]);
    *reinterpret_cast<bf16x8*>(
        &vtb[(size_t)bh * 65536 + d * 1024 + nt * 64 + c2 * 8]) = v;
  }
}

// ---------------- Flash attention: LDS-staged, fragment-order layout ----------
// (unchanged from r9 -- this structure took attn 99.5 -> ~20 us)
__global__ __launch_bounds__(256, 3) void attn_kernel(
    const bf16* __restrict__ QKV, const bf16* __restrict__ Vt,
    bf16* __restrict__ Out) {
  __shared__ bf16 Kb[2][4096];   // 8KB per buffer, fragment-order
  __shared__ bf16 Vb[2][4096];
  const int tid = threadIdx.x;
  const int l = tid & 63;
  const int w = tid >> 6;
  const int ql = l & 31;
  const int hi = l >> 5;
  const int bh = blockIdx.x;       // 0..95 (head-major -> XCD pinning)
  const int b = bh / 12, h = bh % 12;
  const int q0 = blockIdx.y * 128 + w * 32;
  const bf16* Vh = Vt + (size_t)bh * 65536;
  constexpr float L2E = 1.4426950408889634f;

  const int kdst0 = (0 * 4 + w) * 512 + l * 8;
  const int kdst1 = (1 * 4 + w) * 512 + l * 8;
  const bf16* ksrc0 = QKV + (size_t)(b * 1024 + ql) * 2304 + 768 + h * 64 + w * 16 + hi * 8;
  const bf16* ksrc1 = ksrc0 + (size_t)32 * 2304;
  const bf16* vsrc0 = Vh + (size_t)((w & 1) * 32 + ql) * 1024 + ((0 * 4 + w) >> 1) * 16 + hi * 8;
  const bf16* vsrc1 = Vh + (size_t)((w & 1) * 32 + ql) * 1024 + ((1 * 4 + w) >> 1) * 16 + hi * 8;

  const bf16* Qrow = QKV + (size_t)(b * 1024 + q0 + ql) * 2304 + h * 64;
  bf16x8 qf[4];
#pragma unroll
  for (int s = 0; s < 4; s++)
    qf[s] = *reinterpret_cast<const bf16x8*>(&Qrow[s * 16 + hi * 8]);

  f32x16 o[2] = {};
  float ls0 = 0.f, ls1 = 0.f, ls2 = 0.f, ls3 = 0.f;

  GLOAD_LDS16(ksrc0, &Kb[0][kdst0]);
  GLOAD_LDS16(ksrc1, &Kb[0][kdst1]);
  GLOAD_LDS16(vsrc0, &Vb[0][kdst0]);
  GLOAD_LDS16(vsrc1, &Vb[0][kdst1]);
  asm volatile("s_waitcnt vmcnt(0)" ::: "memory");
  __syncthreads();

  int p = 0;
  for (int it = 0; it < 16; ++it) {
    const int kt = it * 64;
    if (it < 15) {
      GLOAD_LDS16(ksrc0 + (size_t)(kt + 64) * 2304, &Kb[p ^ 1][kdst0]);
      GLOAD_LDS16(ksrc1 + (size_t)(kt + 64) * 2304, &Kb[p ^ 1][kdst1]);
      GLOAD_LDS16(vsrc0 + (kt + 64), &Vb[p ^ 1][kdst0]);
      GLOAD_LDS16(vsrc1 + (kt + 64), &Vb[p ^ 1][kdst1]);
    }

    bf16x8 kf[8];
#pragma unroll
    for (int r = 0; r < 8; r++)
      kf[r] = *reinterpret_cast<const bf16x8*>(&Kb[p][r * 512 + l * 8]);
    f32x16 st0 = {}, st1 = {};
    __builtin_amdgcn_s_setprio(1);
#pragma unroll
    for (int s = 0; s < 4; s++) {
      st0 = __builtin_amdgcn_mfma_f32_32x32x16_bf16(kf[s], qf[s], st0, 0, 0, 0);
      st1 = __builtin_amdgcn_mfma_f32_32x32x16_bf16(kf[4 + s], qf[s], st1, 0, 0, 0);
    }
    __builtin_amdgcn_s_setprio(0);

#pragma unroll
    for (int r = 0; r < 16; r++) {
      float a0 = st0[r] * L2E, a1 = st1[r] * L2E;
      float e0, e1;
      asm("v_exp_f32 %0, %1" : "=v"(e0) : "v"(a0));
      asm("v_exp_f32 %0, %1" : "=v"(e1) : "v"(a1));
      st0[r] = e0; st1[r] = e1;
    }
#pragma unroll
    for (int r = 0; r < 16; r += 2) {
      ls0 += st0[r]; ls1 += st0[r + 1];
      ls2 += st1[r]; ls3 += st1[r + 1];
    }

    bf16x8 pfv[4];
#pragma unroll
    for (int t = 0; t < 4; t++) {
      const int c8 = (t & 1) * 8;
      const f32x16& sv = (t < 2) ? st0 : st1;
      uint32_t wA0, wA1, wB0, wB1;
      asm("v_cvt_pk_bf16_f32 %0, %1, %2" : "=v"(wA0) : "v"(sv[c8 + 0]), "v"(sv[c8 + 1]));
      asm("v_cvt_pk_bf16_f32 %0, %1, %2" : "=v"(wA1) : "v"(sv[c8 + 2]), "v"(sv[c8 + 3]));
      asm("v_cvt_pk_bf16_f32 %0, %1, %2" : "=v"(wB0) : "v"(sv[c8 + 4]), "v"(sv[c8 + 5]));
      asm("v_cvt_pk_bf16_f32 %0, %1, %2" : "=v"(wB1) : "v"(sv[c8 + 6]), "v"(sv[c8 + 7]));
      asm("v_permlane32_swap_b32 %0, %1" : "+v"(wA0), "+v"(wB0));
      asm("v_permlane32_swap_b32 %0, %1" : "+v"(wA1), "+v"(wB1));
      union { uint32_t u[4]; bf16x8 v; } pf;
      pf.u[0] = wA0; pf.u[1] = wA1; pf.u[2] = wB0; pf.u[3] = wB1;
      pfv[t] = pf.v;
    }

    bf16x8 vf[8];
#pragma unroll
    for (int r = 0; r < 8; r++)
      vf[r] = *reinterpret_cast<const bf16x8*>(&Vb[p][r * 512 + l * 8]);
    __builtin_amdgcn_s_setprio(1);
#pragma unroll
    for (int t = 0; t < 4; t++) {
      o[0] = __builtin_amdgcn_mfma_f32_32x32x16_bf16(vf[t * 2 + 0], pfv[t], o[0], 0, 0, 0);
      o[1] = __builtin_amdgcn_mfma_f32_32x32x16_bf16(vf[t * 2 + 1], pfv[t], o[1], 0, 0, 0);
    }
    __builtin_amdgcn_s_setprio(0);

    asm volatile("s_waitcnt vmcnt(0)" ::: "memory");
    __syncthreads();
    p ^= 1;
  }

  float lsum = (ls0 + ls1) + (ls2 + ls3);
  lsum += __shfl_xor(lsum, 32);
  const float rl = 1.0f / lsum;
  bf16* orow = Out + (size_t)(b * 1024 + q0 + ql) * 768 + h * 64;
#pragma unroll
  for (int dh = 0; dh < 2; dh++)
#pragma unroll
    for (int rq = 0; rq < 4; rq++) {
      union { ushort us[4]; uint2 v; } pk;
#pragma unroll
      for (int i = 0; i < 4; i++) {
        const bf16 hv = (bf16)(o[dh][rq * 4 + i] * rl);
        pk.us[i] = __builtin_bit_cast(ushort, hv);
      }
      *reinterpret_cast<uint2*>(&orow[dh * 32 + rq * 8 + hi * 4]) = pk.v;
    }
}

// ---------------- launch ------------------------------------------------------
extern "C" void kernel_launch(void* const* d_in, const int* in_sizes, int n_in,
                              void* d_out, int out_size, void* d_ws, size_t ws_size,
                              hipStream_t stream) {
  const float* x = (const float*)d_in[0];
  const float* w_qkv = (const float*)d_in[1];
  const float* w_fc = (const float*)d_in[2];
  const float* b_fc = (const float*)d_in[3];
  float* out = (float*)d_out;
  char* ws = (char*)d_ws;

  bf16* xb = (bf16*)(ws);                    // 8192x768   (dead after gemm256)
  bf16* vtb = (bf16*)(ws);                   // 96x64x1024 (aliases xb -- safe)
  bf16* wqkb = (bf16*)(ws + 12582912);       // 2304x768
  bf16* wfcb = (bf16*)(ws + 16121856);       // 768x768
  bf16* qkvb = (bf16*)(ws + 17301504);       // 8192x2304
  bf16* aob = (bf16*)(ws + 55050240);        // 8192x768

  cvt_f32_bf16<<<2048, 256, 0, stream>>>(x, xb, 6291456 / 4);
  cvt_f32_bf16<<<1728, 256, 0, stream>>>(w_qkv, wqkb, 1769472 / 4);
  cvt_f32_bf16<<<576, 256, 0, stream>>>(w_fc, wfcb, 589824 / 4);

  gemm256<<<dim3(32, 9), 512, 0, stream>>>(xb, wqkb, 8192, 2304, 768, qkvb);

  vtrans<<<dim3(96, 16), 256, 0, stream>>>(qkvb, vtb);

  attn_kernel<<<dim3(96, 8), 256, 0, stream>>>(qkvb, vtb, aob);

  gemm_bt<1><<<dim3(32, 6), 512, 0, stream>>>(aob, wfcb, 8192, 768, 768,
                                              nullptr, out, b_fc);
}